// Round 5
// baseline (53.315 us; speedup 1.0000x reference)
//
#include <hip/hip_runtime.h>
#include <math.h>

#define BATCH 8
#define NPTS  256
#define HDIM  128
#define TOTAL (BATCH * NPTS)   // 2048

#define NEG_LOG2E -1.4426950408889634f
#define NEG_LN2   -0.6931471805599453f

typedef float f2 __attribute__((ext_vector_type(2)));

// ---------------------------------------------------------------------------
// Kernel 1: per-row projections + constant folding + out-zeroing.
//   A'[t,c]  = (h@Wa)[t,c] * (-log2e)   quad-interleaved channel-major:
//              A_T4[(c>>2)*4*TOTAL + 4*t + (c&3)]
//   Bb'[t,c] = ((h@Wb)[t,c] + b1[c]) * (-log2e)   row-major
//   wdx[c]   = W1[2H,c] * (-log2e),  w2x[c] = W2[c] * (-ln2)
// pre2 = A' + Bb' + dist*wdx  =>  silu(pre)*W2 = w2x * pre2 / (1 + 2^pre2).
// Also zeroes out[] so the pair kernel can atomicAdd (stream-ordered).
// ---------------------------------------------------------------------------
__global__ __launch_bounds__(HDIM) void evh_prep_kernel(
    const float* __restrict__ h, const float* __restrict__ W1,
    const float* __restrict__ b1, const float* __restrict__ W2,
    float* __restrict__ A_T4, float* __restrict__ Bb,
    float* __restrict__ wdx, float* __restrict__ w2x,
    float* __restrict__ out)
{
    __shared__ float hrow[HDIM];
    const int t = blockIdx.x;
    const int c = threadIdx.x;
    hrow[c] = h[t * HDIM + c];
    if (t == 0) {
        wdx[c] = W1[2 * HDIM * HDIM + c] * NEG_LOG2E;
        w2x[c] = W2[c] * NEG_LN2;
    }
    if (c < 3) out[t * 3 + c] = 0.f;
    __syncthreads();

    float a = 0.f, bsum = 0.f;
#pragma unroll 8
    for (int k = 0; k < HDIM; ++k) {
        const float hv = hrow[k];
        a    = fmaf(hv, W1[k * HDIM + c], a);
        bsum = fmaf(hv, W1[(HDIM + k) * HDIM + c], bsum);
    }
    A_T4[(c >> 2) * (4 * TOTAL) + 4 * t + (c & 3)] = a * NEG_LOG2E;
    Bb[t * HDIM + c] = (bsum + b1[c]) * NEG_LOG2E;
}

// ---------------------------------------------------------------------------
// Kernel 2: pairwise pass, channel-QUARTER split + packed fp32 math.
// Block = (batch b, target-pair i0..i0+1, quarter ch). 4096 blocks,
// 256 threads = source j. Each thread: 2 i's x 32 channels = 64 cells.
// Uniform operands from block-uniform addresses (scalar loads); A' loads
// coalesced dwordx4, 4 in flight per group. Packed (v_pk_*) VALU ops,
// packed accumulators. Partial v -> atomicAdd.
// ---------------------------------------------------------------------------
__global__ __launch_bounds__(256, 4) void evh_pair_kernel(
    const float* __restrict__ A_T4, const float* __restrict__ Bb,
    const float* __restrict__ wdx, const float* __restrict__ w2x,
    const float* __restrict__ pos, const float* __restrict__ b2,
    float* __restrict__ out)
{
    const int blk = blockIdx.x;                 // 0..4095
    const int ch  = blk & 3;                    // channel quarter
    const int b   = blk >> 9;                   // batch
    const int i0  = ((blk >> 2) & 127) * 2;     // target pair base
    const int tid = threadIdx.x;                // = j within batch
    const int brow  = b * NPTS;
    const int row_j = brow + tid;

    const float pjx = pos[row_j * 3 + 0];
    const float pjy = pos[row_j * 3 + 1];
    const float pjz = pos[row_j * 3 + 2];

    float dx0, dy0, dz0, dx1, dy1, dz1;
    f2 d0, d1;
    {
        const int r0 = brow + i0, r1 = r0 + 1;
        dx0 = pjx - pos[r0 * 3 + 0];
        dy0 = pjy - pos[r0 * 3 + 1];
        dz0 = pjz - pos[r0 * 3 + 2];
        const float t0 = sqrtf(dx0 * dx0 + dy0 * dy0 + dz0 * dz0);
        d0.x = t0; d0.y = t0;
        dx1 = pjx - pos[r1 * 3 + 0];
        dy1 = pjy - pos[r1 * 3 + 1];
        dz1 = pjz - pos[r1 * 3 + 2];
        const float t1 = sqrtf(dx1 * dx1 + dy1 * dy1 + dz1 * dz1);
        d1.x = t1; d1.y = t1;
    }

    // block-uniform operand pointers (scalar-load friendly)
    const float* __restrict__ bb0p = Bb + (size_t)(brow + i0) * HDIM + ch * 32;
    const float* __restrict__ bb1p = bb0p + HDIM;
    const float* __restrict__ wdp  = wdx + ch * 32;
    const float* __restrict__ w2p  = w2x + ch * 32;
    const float* __restrict__ ap   = A_T4 + 4 * row_j
                                     + (size_t)(ch * 8) * (4 * TOTAL);

    f2 acc0 = {0.f, 0.f}, acc1 = {0.f, 0.f};

    // one packed 2-channel cell-pair: t = a + bb + dist*wd;
    // acc += (w2*t) * rcp(1 + 2^t)
#define PAIR(A2, B2, WD2, W22, ACC, DIST2)                              \
    {                                                                   \
        const f2 t = __builtin_elementwise_fma((DIST2), (WD2), (A2) + (B2)); \
        f2 e; e.x = __builtin_amdgcn_exp2f(t.x);                        \
              e.y = __builtin_amdgcn_exp2f(t.y);                        \
        const f2 dpl = e + 1.0f;                                        \
        f2 r; r.x = __builtin_amdgcn_rcpf(dpl.x);                       \
              r.y = __builtin_amdgcn_rcpf(dpl.y);                       \
        ACC = __builtin_elementwise_fma((W22) * t, r, ACC);             \
    }

#pragma unroll
    for (int g = 0; g < 2; ++g) {
        float4 a[4];
#pragma unroll
        for (int q = 0; q < 4; ++q)
            a[q] = *reinterpret_cast<const float4*>(
                       ap + (size_t)(g * 4 + q) * (4 * TOTAL));
#pragma unroll
        for (int q = 0; q < 4; ++q) {
            const int qq = g * 4 + q;
            const float4 b0 = *reinterpret_cast<const float4*>(bb0p + 4 * qq);
            const float4 b1 = *reinterpret_cast<const float4*>(bb1p + 4 * qq);
            const float4 wd = *reinterpret_cast<const float4*>(wdp + 4 * qq);
            const float4 w2 = *reinterpret_cast<const float4*>(w2p + 4 * qq);
            const f2 alo = {a[q].x, a[q].y}, ahi = {a[q].z, a[q].w};
            const f2 b0lo = {b0.x, b0.y},   b0hi = {b0.z, b0.w};
            const f2 b1lo = {b1.x, b1.y},   b1hi = {b1.z, b1.w};
            const f2 wdlo = {wd.x, wd.y},   wdhi = {wd.z, wd.w};
            const f2 w2lo = {w2.x, w2.y},   w2hi = {w2.z, w2.w};

            PAIR(alo, b0lo, wdlo, w2lo, acc0, d0)
            PAIR(ahi, b0hi, wdhi, w2hi, acc0, d0)
            PAIR(alo, b1lo, wdlo, w2lo, acc1, d1)
            PAIR(ahi, b1hi, wdhi, w2hi, acc1, d1)
        }
    }
#undef PAIR

    // epilogue: partial v over this quarter; b2 contributed only by ch 0.
    const float cext = (ch == 0) ? b2[0] : 0.f;
    const int wave = tid >> 6;
    const int lane = tid & 63;

    const float c0 = acc0.x + acc0.y + cext;
    const float c1 = acc1.x + acc1.y + cext;
    float v0x = c0 * dx0, v0y = c0 * dy0, v0z = c0 * dz0;
    float v1x = c1 * dx1, v1y = c1 * dy1, v1z = c1 * dz1;
#pragma unroll
    for (int off = 32; off >= 1; off >>= 1) {
        v0x += __shfl_xor(v0x, off, 64);
        v0y += __shfl_xor(v0y, off, 64);
        v0z += __shfl_xor(v0z, off, 64);
        v1x += __shfl_xor(v1x, off, 64);
        v1y += __shfl_xor(v1y, off, 64);
        v1z += __shfl_xor(v1z, off, 64);
    }

    __shared__ float vsh[4][6];
    if (lane == 0) {
        vsh[wave][0] = v0x; vsh[wave][1] = v0y; vsh[wave][2] = v0z;
        vsh[wave][3] = v1x; vsh[wave][4] = v1y; vsh[wave][5] = v1z;
    }
    __syncthreads();
    if (tid < 6) {
        const float val = vsh[0][tid] + vsh[1][tid] + vsh[2][tid] + vsh[3][tid];
        const int s = tid / 3, comp = tid % 3;
        atomicAdd(&out[(brow + i0 + s) * 3 + comp], val);
    }
}

extern "C" void kernel_launch(void* const* d_in, const int* in_sizes, int n_in,
                              void* d_out, int out_size, void* d_ws, size_t ws_size,
                              hipStream_t stream) {
    const float* h   = (const float*)d_in[0];  // (2048, 128)
    const float* pos = (const float*)d_in[1];  // (2048, 3)
    // d_in[2] = batch indices (int64) — contiguous per batch, unused
    const float* W1  = (const float*)d_in[3];  // (257, 128)
    const float* b1  = (const float*)d_in[4];  // (128,)
    const float* W2  = (const float*)d_in[5];  // (128, 1)
    const float* b2  = (const float*)d_in[6];  // (1,)
    float* out = (float*)d_out;                // (2048, 3)

    float* A_T4 = (float*)d_ws;                // 1 MB
    float* Bb   = A_T4 + TOTAL * HDIM;         // 1 MB
    float* wdx  = Bb + TOTAL * HDIM;           // 512 B
    float* w2x  = wdx + HDIM;                  // 512 B

    evh_prep_kernel<<<TOTAL, HDIM, 0, stream>>>(h, W1, b1, W2,
                                                A_T4, Bb, wdx, w2x, out);
    evh_pair_kernel<<<4 * TOTAL, 256, 0, stream>>>(A_T4, Bb, wdx, w2x,
                                                   pos, b2, out);
}

// Round 6
// 39.134 us; speedup vs baseline: 1.3624x; 1.3624x over previous
//
#include <hip/hip_runtime.h>
#include <math.h>

#define BATCH 8
#define NPTS  256
#define HDIM  128
#define TOTAL (BATCH * NPTS)   // 2048
#define IT    4                // targets (i) per block
#define QCH   32               // channels per block (quarter of 128)

#define NEG_LOG2E -1.4426950408889634f
#define NEG_LN2   -0.6931471805599453f

// ---------------------------------------------------------------------------
// Kernel 1: per-row projections + constant folding + out-zeroing.
//   A'[t,c]  = (h@Wa)[t,c] * (-log2e)   quad-interleaved channel-major:
//              A_T4[(c>>2)*4*TOTAL + 4*t + (c&3)]
//   Bb'[t,c] = ((h@Wb)[t,c] + b1[c]) * (-log2e)   row-major
//   wdx[c]   = W1[2H,c] * (-log2e),  w2x[c] = W2[c] * (-ln2)
// pre2 = A' + Bb' + dist*wdx  =>  silu(pre)*W2 = w2x * pre2 / (1 + 2^pre2).
// Also zeroes out[] so the pair kernel can atomicAdd (stream-ordered).
// ---------------------------------------------------------------------------
__global__ __launch_bounds__(HDIM) void evh_prep_kernel(
    const float* __restrict__ h, const float* __restrict__ W1,
    const float* __restrict__ b1, const float* __restrict__ W2,
    float* __restrict__ A_T4, float* __restrict__ Bb,
    float* __restrict__ wdx, float* __restrict__ w2x,
    float* __restrict__ out)
{
    __shared__ float hrow[HDIM];
    const int t = blockIdx.x;
    const int c = threadIdx.x;
    hrow[c] = h[t * HDIM + c];
    if (t == 0) {
        wdx[c] = W1[2 * HDIM * HDIM + c] * NEG_LOG2E;
        w2x[c] = W2[c] * NEG_LN2;
    }
    if (c < 3) out[t * 3 + c] = 0.f;
    __syncthreads();

    float a = 0.f, bsum = 0.f;
#pragma unroll 8
    for (int k = 0; k < HDIM; ++k) {
        const float hv = hrow[k];
        a    = fmaf(hv, W1[k * HDIM + c], a);
        bsum = fmaf(hv, W1[(HDIM + k) * HDIM + c], bsum);
    }
    A_T4[(c >> 2) * (4 * TOTAL) + 4 * t + (c & 3)] = a * NEG_LOG2E;
    Bb[t * HDIM + c] = (bsum + b1[c]) * NEG_LOG2E;
}

// ---------------------------------------------------------------------------
// Kernel 2: pairwise pass. Block = (batch b, 4 targets i0..i0+3, channel
// quarter ch). 2048 blocks, 256 threads = source j. Each thread: 4 i's x
// 32 channels = 128 cells (same as the r4 champion), but uniform-load
// traffic per cell is ~3x lower and there are 4 independent acc chains.
// All 8 A-quads are prefetched to registers before the cell stream.
// Scalar cell math (no packing - r5's mov-storm lesson). atomicAdd epilogue.
// ---------------------------------------------------------------------------
__global__ __launch_bounds__(256) void evh_pair_kernel(
    const float* __restrict__ A_T4, const float* __restrict__ Bb,
    const float* __restrict__ wdx, const float* __restrict__ w2x,
    const float* __restrict__ pos, const float* __restrict__ b2,
    float* __restrict__ out)
{
    const int blk = blockIdx.x;                 // 0..2047
    const int ch  = blk & 3;                    // channel quarter
    const int ig  = (blk >> 2) & 63;            // i-group
    const int b   = blk >> 8;                   // batch
    const int i0  = ig * IT;
    const int tid = threadIdx.x;                // = j within batch
    const int brow  = b * NPTS;
    const int row_j = brow + tid;

    const float pjx = pos[row_j * 3 + 0];
    const float pjy = pos[row_j * 3 + 1];
    const float pjz = pos[row_j * 3 + 2];

    float dx[IT], dy[IT], dz[IT], dist[IT];
#pragma unroll
    for (int s = 0; s < IT; ++s) {
        const int ri = brow + i0 + s;
        dx[s] = pjx - pos[ri * 3 + 0];
        dy[s] = pjy - pos[ri * 3 + 1];
        dz[s] = pjz - pos[ri * 3 + 2];
        dist[s] = sqrtf(dx[s] * dx[s] + dy[s] * dy[s] + dz[s] * dz[s]);
    }

    // prefetch this thread's 8 A-quads (32 channels) into registers
    const float* __restrict__ ap = A_T4 + 4 * row_j
                                   + (size_t)(ch * 8) * (4 * TOTAL);
    float4 a[8];
#pragma unroll
    for (int q = 0; q < 8; ++q)
        a[q] = *reinterpret_cast<const float4*>(ap + (size_t)q * (4 * TOTAL));

    // block-uniform operand pointers (scalar-load friendly)
    const float* __restrict__ bbp = Bb + (size_t)(brow + i0) * HDIM + ch * QCH;
    const float* __restrict__ wdp = wdx + ch * QCH;
    const float* __restrict__ w2p = w2x + ch * QCH;

    float acc[IT] = {0.f, 0.f, 0.f, 0.f};

#define CELL(AK, BK, WDK, W2K, ACC, D)                                  \
    {                                                                   \
        const float pre2 = fmaf((D), (WDK), (AK) + (BK));               \
        const float e = __builtin_amdgcn_exp2f(pre2);                   \
        const float r = __builtin_amdgcn_rcpf(1.f + e);                 \
        ACC = fmaf((W2K), pre2 * r, ACC);                               \
    }

#pragma unroll
    for (int q = 0; q < 8; ++q) {
        const float4 wd = *reinterpret_cast<const float4*>(wdp + 4 * q);
        const float4 w2 = *reinterpret_cast<const float4*>(w2p + 4 * q);
#pragma unroll
        for (int s = 0; s < IT; ++s) {
            const float4 bb = *reinterpret_cast<const float4*>(
                                  bbp + (size_t)s * HDIM + 4 * q);
            CELL(a[q].x, bb.x, wd.x, w2.x, acc[s], dist[s])
            CELL(a[q].y, bb.y, wd.y, w2.y, acc[s], dist[s])
            CELL(a[q].z, bb.z, wd.z, w2.z, acc[s], dist[s])
            CELL(a[q].w, bb.w, wd.w, w2.w, acc[s], dist[s])
        }
    }
#undef CELL

    // epilogue: partial v over this quarter; b2 contributed only by ch 0.
    const float cext = (ch == 0) ? b2[0] : 0.f;
    const int wave = tid >> 6;
    const int lane = tid & 63;

    float v[IT][3];
#pragma unroll
    for (int s = 0; s < IT; ++s) {
        const float co = acc[s] + cext;
        v[s][0] = co * dx[s];
        v[s][1] = co * dy[s];
        v[s][2] = co * dz[s];
    }
#pragma unroll
    for (int off = 32; off >= 1; off >>= 1) {
#pragma unroll
        for (int s = 0; s < IT; ++s) {
            v[s][0] += __shfl_xor(v[s][0], off, 64);
            v[s][1] += __shfl_xor(v[s][1], off, 64);
            v[s][2] += __shfl_xor(v[s][2], off, 64);
        }
    }

    __shared__ float vsh[4][IT * 3];
    if (lane == 0) {
#pragma unroll
        for (int s = 0; s < IT; ++s) {
            vsh[wave][s * 3 + 0] = v[s][0];
            vsh[wave][s * 3 + 1] = v[s][1];
            vsh[wave][s * 3 + 2] = v[s][2];
        }
    }
    __syncthreads();
    if (tid < IT * 3) {
        const float val = vsh[0][tid] + vsh[1][tid] + vsh[2][tid] + vsh[3][tid];
        const int s = tid / 3, comp = tid % 3;
        atomicAdd(&out[(brow + i0 + s) * 3 + comp], val);
    }
}

extern "C" void kernel_launch(void* const* d_in, const int* in_sizes, int n_in,
                              void* d_out, int out_size, void* d_ws, size_t ws_size,
                              hipStream_t stream) {
    const float* h   = (const float*)d_in[0];  // (2048, 128)
    const float* pos = (const float*)d_in[1];  // (2048, 3)
    // d_in[2] = batch indices (int64) — contiguous per batch, unused
    const float* W1  = (const float*)d_in[3];  // (257, 128)
    const float* b1  = (const float*)d_in[4];  // (128,)
    const float* W2  = (const float*)d_in[5];  // (128, 1)
    const float* b2  = (const float*)d_in[6];  // (1,)
    float* out = (float*)d_out;                // (2048, 3)

    float* A_T4 = (float*)d_ws;                // 1 MB
    float* Bb   = A_T4 + TOTAL * HDIM;         // 1 MB
    float* wdx  = Bb + TOTAL * HDIM;           // 512 B
    float* w2x  = wdx + HDIM;                  // 512 B

    evh_prep_kernel<<<TOTAL, HDIM, 0, stream>>>(h, W1, b1, W2,
                                                A_T4, Bb, wdx, w2x, out);
    // blocks = BATCH * (NPTS/IT) * 4 quarters = 2048
    evh_pair_kernel<<<BATCH * (NPTS / IT) * 4, 256, 0, stream>>>(
        A_T4, Bb, wdx, w2x, pos, b2, out);
}

// Round 7
// 33.868 us; speedup vs baseline: 1.5742x; 1.1555x over previous
//
#include <hip/hip_runtime.h>
#include <math.h>

#define BATCH 8
#define NPTS  256
#define HDIM  128
#define TOTAL (BATCH * NPTS)   // 2048

#define NEG_LOG2E -1.4426950408889634f
#define NEG_LN2   -0.6931471805599453f

// ---------------------------------------------------------------------------
// Kernel 1: per-row projections + constant folding + out-zeroing.
//   A'[t,c]  = (h@Wa)[t,c] * (-log2e)   quad-interleaved channel-major:
//              A_T4[(c>>2)*4*TOTAL + 4*t + (c&3)]
//   Bb'[t,c] = ((h@Wb)[t,c] + b1[c]) * (-log2e)   row-major
//   wdx[c]   = W1[2H,c] * (-log2e),  w2x[c] = W2[c] * (-ln2)
// pre2 = A' + Bb' + dist*wdx  =>  silu(pre)*W2 = w2x * pre2 / (1 + 2^pre2).
// Also zeroes out[] so the pair kernel can atomicAdd (stream-ordered).
// ---------------------------------------------------------------------------
__global__ __launch_bounds__(HDIM) void evh_prep_kernel(
    const float* __restrict__ h, const float* __restrict__ W1,
    const float* __restrict__ b1, const float* __restrict__ W2,
    float* __restrict__ A_T4, float* __restrict__ Bb,
    float* __restrict__ wdx, float* __restrict__ w2x,
    float* __restrict__ out)
{
    __shared__ float hrow[HDIM];
    const int t = blockIdx.x;
    const int c = threadIdx.x;
    hrow[c] = h[t * HDIM + c];
    if (t == 0) {
        wdx[c] = W1[2 * HDIM * HDIM + c] * NEG_LOG2E;
        w2x[c] = W2[c] * NEG_LN2;
    }
    if (c < 3) out[t * 3 + c] = 0.f;
    __syncthreads();

    float a = 0.f, bsum = 0.f;
#pragma unroll 8
    for (int k = 0; k < HDIM; ++k) {
        const float hv = hrow[k];
        a    = fmaf(hv, W1[k * HDIM + c], a);
        bsum = fmaf(hv, W1[(HDIM + k) * HDIM + c], bsum);
    }
    A_T4[(c >> 2) * (4 * TOTAL) + 4 * t + (c & 3)] = a * NEG_LOG2E;
    Bb[t * HDIM + c] = (bsum + b1[c]) * NEG_LOG2E;
}

// ---------------------------------------------------------------------------
// Kernel 2: pairwise pass, channel-half split (r4 champion shape) with a
// 4-way shared-reciprocal cell cluster. Block = (batch b, target pair,
// channel half ch). 2048 blocks, 256 threads = source j. Each thread:
// 2 i's x 64 channels = 128 cells. One v_rcp per 4 cells (product trick);
// one v_exp per cell. Uniform operands via block-uniform (scalar) loads;
// A' via coalesced dwordx4. atomicAdd epilogue; b2 added by half 0 only.
// ---------------------------------------------------------------------------
__global__ __launch_bounds__(256, 8) void evh_pair_kernel(
    const float* __restrict__ A_T4, const float* __restrict__ Bb,
    const float* __restrict__ wdx, const float* __restrict__ w2x,
    const float* __restrict__ pos, const float* __restrict__ b2,
    float* __restrict__ out)
{
    const int blk = blockIdx.x;                 // 0..2047
    const int ch  = blk & 1;                    // channel half
    const int b   = blk >> 8;                   // batch
    const int i0  = ((blk >> 1) & 127) * 2;     // target pair base
    const int tid = threadIdx.x;                // = j within batch
    const int brow  = b * NPTS;
    const int row_j = brow + tid;

    const float pjx = pos[row_j * 3 + 0];
    const float pjy = pos[row_j * 3 + 1];
    const float pjz = pos[row_j * 3 + 2];

    float dx0, dy0, dz0, dist0, dx1, dy1, dz1, dist1;
    {
        const int r0 = brow + i0, r1 = r0 + 1;
        dx0 = pjx - pos[r0 * 3 + 0];
        dy0 = pjy - pos[r0 * 3 + 1];
        dz0 = pjz - pos[r0 * 3 + 2];
        dist0 = sqrtf(dx0 * dx0 + dy0 * dy0 + dz0 * dz0);
        dx1 = pjx - pos[r1 * 3 + 0];
        dy1 = pjy - pos[r1 * 3 + 1];
        dz1 = pjz - pos[r1 * 3 + 2];
        dist1 = sqrtf(dx1 * dx1 + dy1 * dy1 + dz1 * dz1);
    }

    // block-uniform operand pointers (scalar-load friendly)
    const float* __restrict__ bb0p = Bb + (size_t)(brow + i0) * HDIM + ch * 64;
    const float* __restrict__ bb1p = bb0p + HDIM;
    const float* __restrict__ wdp  = wdx + ch * 64;
    const float* __restrict__ w2p  = w2x + ch * 64;
    const float* __restrict__ ap   = A_T4 + 4 * row_j
                                     + (size_t)(ch * 16) * (4 * TOTAL);

    float acc0 = 0.f, acc1 = 0.f;

    // 4 cells, ONE v_rcp: d_i = 1 + 2^t_i; invert all four via product trick.
#define CLUSTER(AQ, BQ, WDQ, W2Q, ACC, D)                               \
    {                                                                   \
        const float t0 = fmaf((D), (WDQ).x, (AQ).x + (BQ).x);           \
        const float t1 = fmaf((D), (WDQ).y, (AQ).y + (BQ).y);           \
        const float t2 = fmaf((D), (WDQ).z, (AQ).z + (BQ).z);           \
        const float t3 = fmaf((D), (WDQ).w, (AQ).w + (BQ).w);           \
        const float d0 = 1.f + __builtin_amdgcn_exp2f(t0);              \
        const float d1 = 1.f + __builtin_amdgcn_exp2f(t1);              \
        const float d2 = 1.f + __builtin_amdgcn_exp2f(t2);              \
        const float d3 = 1.f + __builtin_amdgcn_exp2f(t3);              \
        const float p01 = d0 * d1, p23 = d2 * d3;                       \
        const float r   = __builtin_amdgcn_rcpf(p01 * p23);             \
        const float r01 = r * p23, r23 = r * p01;                       \
        ACC = fmaf((W2Q).x * t0, r01 * d1, ACC);                        \
        ACC = fmaf((W2Q).y * t1, r01 * d0, ACC);                        \
        ACC = fmaf((W2Q).z * t2, r23 * d3, ACC);                        \
        ACC = fmaf((W2Q).w * t3, r23 * d2, ACC);                        \
    }

#pragma unroll 4
    for (int q = 0; q < 16; ++q) {
        const float4 a  = *reinterpret_cast<const float4*>(
                              ap + (size_t)q * (4 * TOTAL));
        const float4 b0 = *reinterpret_cast<const float4*>(bb0p + 4 * q);
        const float4 b1 = *reinterpret_cast<const float4*>(bb1p + 4 * q);
        const float4 wd = *reinterpret_cast<const float4*>(wdp + 4 * q);
        const float4 w2 = *reinterpret_cast<const float4*>(w2p + 4 * q);

        CLUSTER(a, b0, wd, w2, acc0, dist0)
        CLUSTER(a, b1, wd, w2, acc1, dist1)
    }
#undef CLUSTER

    // epilogue: partial v over this half; b2 contributed only by half 0.
    const float cext = (ch == 0) ? b2[0] : 0.f;
    const int wave = tid >> 6;
    const int lane = tid & 63;

    const float c0 = acc0 + cext;
    const float c1 = acc1 + cext;
    float v0x = c0 * dx0, v0y = c0 * dy0, v0z = c0 * dz0;
    float v1x = c1 * dx1, v1y = c1 * dy1, v1z = c1 * dz1;
#pragma unroll
    for (int off = 32; off >= 1; off >>= 1) {
        v0x += __shfl_xor(v0x, off, 64);
        v0y += __shfl_xor(v0y, off, 64);
        v0z += __shfl_xor(v0z, off, 64);
        v1x += __shfl_xor(v1x, off, 64);
        v1y += __shfl_xor(v1y, off, 64);
        v1z += __shfl_xor(v1z, off, 64);
    }

    __shared__ float vsh[4][6];
    if (lane == 0) {
        vsh[wave][0] = v0x; vsh[wave][1] = v0y; vsh[wave][2] = v0z;
        vsh[wave][3] = v1x; vsh[wave][4] = v1y; vsh[wave][5] = v1z;
    }
    __syncthreads();
    if (tid < 6) {
        const float val = vsh[0][tid] + vsh[1][tid] + vsh[2][tid] + vsh[3][tid];
        const int s = tid / 3, comp = tid % 3;
        atomicAdd(&out[(brow + i0 + s) * 3 + comp], val);
    }
}

extern "C" void kernel_launch(void* const* d_in, const int* in_sizes, int n_in,
                              void* d_out, int out_size, void* d_ws, size_t ws_size,
                              hipStream_t stream) {
    const float* h   = (const float*)d_in[0];  // (2048, 128)
    const float* pos = (const float*)d_in[1];  // (2048, 3)
    // d_in[2] = batch indices (int64) — contiguous per batch, unused
    const float* W1  = (const float*)d_in[3];  // (257, 128)
    const float* b1  = (const float*)d_in[4];  // (128,)
    const float* W2  = (const float*)d_in[5];  // (128, 1)
    const float* b2  = (const float*)d_in[6];  // (1,)
    float* out = (float*)d_out;                // (2048, 3)

    float* A_T4 = (float*)d_ws;                // 1 MB
    float* Bb   = A_T4 + TOTAL * HDIM;         // 1 MB
    float* wdx  = Bb + TOTAL * HDIM;           // 512 B
    float* w2x  = wdx + HDIM;                  // 512 B

    evh_prep_kernel<<<TOTAL, HDIM, 0, stream>>>(h, W1, b1, W2,
                                                A_T4, Bb, wdx, w2x, out);
    evh_pair_kernel<<<TOTAL, 256, 0, stream>>>(A_T4, Bb, wdx, w2x,
                                               pos, b2, out);
}

// Round 8
// 33.683 us; speedup vs baseline: 1.5829x; 1.0055x over previous
//
#include <hip/hip_runtime.h>
#include <math.h>

#define BATCH 8
#define NPTS  256
#define HDIM  128
#define TOTAL (BATCH * NPTS)   // 2048

#define NEG_LOG2E -1.4426950408889634f
#define NEG_LN2   -0.6931471805599453f

typedef float f2 __attribute__((ext_vector_type(2)));
typedef float f4 __attribute__((ext_vector_type(4)));

// ---------------------------------------------------------------------------
// Kernel 1: per-row projections + constant folding + out-zeroing.
//   A'[t,c]  = (h@Wa)[t,c] * (-log2e)   quad-interleaved channel-major:
//              A_T4[(c>>2)*4*TOTAL + 4*t + (c&3)]
//   Bb'[t,c] = ((h@Wb)[t,c] + b1[c]) * (-log2e)   row-major
//   wdx[c]   = W1[2H,c] * (-log2e),  w2x[c] = W2[c] * (-ln2)
// pre2 = A' + Bb' + dist*wdx  =>  silu(pre)*W2 = w2x * pre2 / (1 + 2^pre2).
// Also zeroes out[] so the pair kernel can atomicAdd (stream-ordered).
// ---------------------------------------------------------------------------
__global__ __launch_bounds__(HDIM) void evh_prep_kernel(
    const float* __restrict__ h, const float* __restrict__ W1,
    const float* __restrict__ b1, const float* __restrict__ W2,
    float* __restrict__ A_T4, float* __restrict__ Bb,
    float* __restrict__ wdx, float* __restrict__ w2x,
    float* __restrict__ out)
{
    __shared__ float hrow[HDIM];
    const int t = blockIdx.x;
    const int c = threadIdx.x;
    hrow[c] = h[t * HDIM + c];
    if (t == 0) {
        wdx[c] = W1[2 * HDIM * HDIM + c] * NEG_LOG2E;
        w2x[c] = W2[c] * NEG_LN2;
    }
    if (c < 3) out[t * 3 + c] = 0.f;
    __syncthreads();

    float a = 0.f, bsum = 0.f;
#pragma unroll 8
    for (int k = 0; k < HDIM; ++k) {
        const float hv = hrow[k];
        a    = fmaf(hv, W1[k * HDIM + c], a);
        bsum = fmaf(hv, W1[(HDIM + k) * HDIM + c], bsum);
    }
    A_T4[(c >> 2) * (4 * TOTAL) + 4 * t + (c & 3)] = a * NEG_LOG2E;
    Bb[t * HDIM + c] = (bsum + b1[c]) * NEG_LOG2E;
}

// ---------------------------------------------------------------------------
// Kernel 2: pairwise pass, r4 champion shape (half-split, 2048 blocks,
// 256 threads = j), inner math in packed f32 (VOP3P) with a 4-cell shared
// reciprocal. f2 values are aligned halves of loaded float4s (no repacks).
// Per 4 cells: 15 VALU + 5 trans (vs r4's 20 VALU + 8 trans).
// ---------------------------------------------------------------------------
__global__ __launch_bounds__(256, 8) void evh_pair_kernel(
    const float* __restrict__ A_T4, const float* __restrict__ Bb,
    const float* __restrict__ wdx, const float* __restrict__ w2x,
    const float* __restrict__ pos, const float* __restrict__ b2,
    float* __restrict__ out)
{
    const int blk = blockIdx.x;                 // 0..2047
    const int ch  = blk & 1;                    // channel half
    const int b   = blk >> 8;                   // batch
    const int i0  = ((blk >> 1) & 127) * 2;     // target pair base
    const int tid = threadIdx.x;                // = j within batch
    const int brow  = b * NPTS;
    const int row_j = brow + tid;

    const float pjx = pos[row_j * 3 + 0];
    const float pjy = pos[row_j * 3 + 1];
    const float pjz = pos[row_j * 3 + 2];

    float dx0, dy0, dz0, dist0, dx1, dy1, dz1, dist1;
    {
        const int r0 = brow + i0, r1 = r0 + 1;
        dx0 = pjx - pos[r0 * 3 + 0];
        dy0 = pjy - pos[r0 * 3 + 1];
        dz0 = pjz - pos[r0 * 3 + 2];
        dist0 = sqrtf(dx0 * dx0 + dy0 * dy0 + dz0 * dz0);
        dx1 = pjx - pos[r1 * 3 + 0];
        dy1 = pjy - pos[r1 * 3 + 1];
        dz1 = pjz - pos[r1 * 3 + 2];
        dist1 = sqrtf(dx1 * dx1 + dy1 * dy1 + dz1 * dz1);
    }
    const f2 dd0 = {dist0, dist0};
    const f2 dd1 = {dist1, dist1};

    // block-uniform operand pointers (scalar-load friendly)
    const float* __restrict__ bb0p = Bb + (size_t)(brow + i0) * HDIM + ch * 64;
    const float* __restrict__ bb1p = bb0p + HDIM;
    const float* __restrict__ wdp  = wdx + ch * 64;
    const float* __restrict__ w2p  = w2x + ch * 64;
    const float* __restrict__ ap   = A_T4 + 4 * row_j
                                     + (size_t)(ch * 16) * (4 * TOTAL);

    f2 acc0l = {0.f, 0.f}, acc0h = {0.f, 0.f};
    f2 acc1l = {0.f, 0.f}, acc1h = {0.f, 0.f};

    // 4 cells (one float4 group, one target), ONE v_rcp via product trick.
    // t = a + bb + d*wd; den = 1 + 2^t; acc += (w2*t) / den.
#define QUAD(AL, AH, BL, BH, WDL, WDH, W2L, W2H, ACCL, ACCH, DD)        \
    {                                                                   \
        const f2 tl = __builtin_elementwise_fma((DD), (WDL), (AL) + (BL)); \
        const f2 th = __builtin_elementwise_fma((DD), (WDH), (AH) + (BH)); \
        f2 el, eh;                                                      \
        el.x = __builtin_amdgcn_exp2f(tl.x);                            \
        el.y = __builtin_amdgcn_exp2f(tl.y);                            \
        eh.x = __builtin_amdgcn_exp2f(th.x);                            \
        eh.y = __builtin_amdgcn_exp2f(th.y);                            \
        const f2 dl = el + 1.0f;                                        \
        const f2 dh = eh + 1.0f;                                        \
        const f2 pr = dl * dh;          /* {d0*d2, d1*d3} */            \
        const float pp = pr.x * pr.y;   /* d0*d1*d2*d3    */            \
        const float rr = __builtin_amdgcn_rcpf(pp);                     \
        const f2 rv = {rr, rr};                                         \
        const f2 sw = {pr.y, pr.x};                                     \
        const f2 s  = rv * sw;          /* {1/(d0d2), 1/(d1d3)} */      \
        const f2 invl = s * dh;         /* {1/d0, 1/d1} */              \
        const f2 invh = s * dl;         /* {1/d2, 1/d3} */              \
        ACCL = __builtin_elementwise_fma((W2L) * tl, invl, ACCL);       \
        ACCH = __builtin_elementwise_fma((W2H) * th, invh, ACCH);       \
    }

#pragma unroll 4
    for (int q = 0; q < 16; ++q) {
        const f4 a  = *reinterpret_cast<const f4*>(ap + (size_t)q * (4 * TOTAL));
        const f4 b0 = *reinterpret_cast<const f4*>(bb0p + 4 * q);
        const f4 b1 = *reinterpret_cast<const f4*>(bb1p + 4 * q);
        const f4 wd = *reinterpret_cast<const f4*>(wdp + 4 * q);
        const f4 w2 = *reinterpret_cast<const f4*>(w2p + 4 * q);
        const f2 al = {a.x, a.y},  ah = {a.z, a.w};
        const f2 b0l = {b0.x, b0.y}, b0h = {b0.z, b0.w};
        const f2 b1l = {b1.x, b1.y}, b1h = {b1.z, b1.w};
        const f2 wdl = {wd.x, wd.y}, wdh = {wd.z, wd.w};
        const f2 w2l = {w2.x, w2.y}, w2h = {w2.z, w2.w};

        QUAD(al, ah, b0l, b0h, wdl, wdh, w2l, w2h, acc0l, acc0h, dd0)
        QUAD(al, ah, b1l, b1h, wdl, wdh, w2l, w2h, acc1l, acc1h, dd1)
    }
#undef QUAD

    // epilogue: partial v over this half; b2 contributed only by half 0.
    const float cext = (ch == 0) ? b2[0] : 0.f;
    const int wave = tid >> 6;
    const int lane = tid & 63;

    const float c0 = acc0l.x + acc0l.y + acc0h.x + acc0h.y + cext;
    const float c1 = acc1l.x + acc1l.y + acc1h.x + acc1h.y + cext;
    float v0x = c0 * dx0, v0y = c0 * dy0, v0z = c0 * dz0;
    float v1x = c1 * dx1, v1y = c1 * dy1, v1z = c1 * dz1;
#pragma unroll
    for (int off = 32; off >= 1; off >>= 1) {
        v0x += __shfl_xor(v0x, off, 64);
        v0y += __shfl_xor(v0y, off, 64);
        v0z += __shfl_xor(v0z, off, 64);
        v1x += __shfl_xor(v1x, off, 64);
        v1y += __shfl_xor(v1y, off, 64);
        v1z += __shfl_xor(v1z, off, 64);
    }

    __shared__ float vsh[4][6];
    if (lane == 0) {
        vsh[wave][0] = v0x; vsh[wave][1] = v0y; vsh[wave][2] = v0z;
        vsh[wave][3] = v1x; vsh[wave][4] = v1y; vsh[wave][5] = v1z;
    }
    __syncthreads();
    if (tid < 6) {
        const float val = vsh[0][tid] + vsh[1][tid] + vsh[2][tid] + vsh[3][tid];
        const int s = tid / 3, comp = tid % 3;
        atomicAdd(&out[(brow + i0 + s) * 3 + comp], val);
    }
}

extern "C" void kernel_launch(void* const* d_in, const int* in_sizes, int n_in,
                              void* d_out, int out_size, void* d_ws, size_t ws_size,
                              hipStream_t stream) {
    const float* h   = (const float*)d_in[0];  // (2048, 128)
    const float* pos = (const float*)d_in[1];  // (2048, 3)
    // d_in[2] = batch indices (int64) — contiguous per batch, unused
    const float* W1  = (const float*)d_in[3];  // (257, 128)
    const float* b1  = (const float*)d_in[4];  // (128,)
    const float* W2  = (const float*)d_in[5];  // (128, 1)
    const float* b2  = (const float*)d_in[6];  // (1,)
    float* out = (float*)d_out;                // (2048, 3)

    float* A_T4 = (float*)d_ws;                // 1 MB
    float* Bb   = A_T4 + TOTAL * HDIM;         // 1 MB
    float* wdx  = Bb + TOTAL * HDIM;           // 512 B
    float* w2x  = wdx + HDIM;                  // 512 B

    evh_prep_kernel<<<TOTAL, HDIM, 0, stream>>>(h, W1, b1, W2,
                                                A_T4, Bb, wdx, w2x, out);
    evh_pair_kernel<<<TOTAL, 256, 0, stream>>>(A_T4, Bb, wdx, w2x,
                                               pos, b2, out);
}